// Round 2
// baseline (4622.934 us; speedup 1.0000x reference)
//
#include <hip/hip_runtime.h>
#include <stdint.h>

// ---------------------------------------------------------------------------
// pcnn: 8-layer tiny CNN on 32768 5x5x8 patches, softmax over 6 predicted
// kernel weights, per-pixel color mix. f32 compute throughout.
//
// Round 2: dtype-sniffing hedge. The reference declares float32 tensors but
// round-1's NaN (inf-inf in softmax) is the signature of reading f32 buffers
// as bf16. A deterministic bit-pattern sniff of w0 picks the interpretation
// (f32 vs bf16) uniformly per block for all loads/stores.
// ---------------------------------------------------------------------------

#define PPB   8      // patches per block
#define NTHR  256    // 8 patches x 32 slots (25 pixels active)

// f32 workspace layout (element offsets)
#define OFF_W0 0       // [t9][o25][c8]      = 1800
#define OFF_B0 1800    // [25]
#define OFF_WM 1825    // [l6][t9][o25][c25] = 33750
#define OFF_BM 35575   // [l6][o25]          = 150
#define OFF_WL 35725   // [t9][o6][c25]      = 1350
#define OFF_BL 37075   // [6]
#define OFF_WP 37081   // [oc18][ic3][pix25] = 1350
#define OFF_BP 38431   // [18]
#define WS_FLOATS 38449

__device__ __forceinline__ float b2f(unsigned short u) {
  union { unsigned int u; float f; } v; v.u = ((unsigned int)u) << 16; return v.f;
}
__device__ __forceinline__ unsigned short f2b(float f) {
  union { float f; unsigned int u; } v; v.f = f;
  unsigned int r = v.u + 0x7fffu + ((v.u >> 16) & 1u);  // round-nearest-even
  return (unsigned short)(r >> 16);
}

// True if the underlying data stream is f32 (so ushort view = float halves).
// Genuine bf16 N(0,0.1) weights: all |v| < 1. f32 mantissa halves viewed as
// bf16: random exponent fields -> values > 4 (or inf/nan) with certainty
// among 64 samples. Deterministic per dataset; wave-uniform.
__device__ __forceinline__ bool sniff_is_f32(const unsigned short* __restrict__ w0raw) {
  int hits = 0;
  #pragma unroll
  for (int i = 0; i < 64; ++i) {
    unsigned short u = w0raw[i];
    unsigned int e = (u >> 7) & 0xFFu;       // bf16 exponent field
    if (e >= 130u) ++hits;                   // |v| >= 4, or inf/nan
  }
  return hits > 0;
}

__device__ __forceinline__ float ldw(const void* p, int idx, bool f32) {
  return f32 ? ((const float*)p)[idx] : b2f(((const unsigned short*)p)[idx]);
}

// Convert weights -> f32 in d_ws, permuted so tap index is outermost
// (conv loops then have wave-uniform addresses -> scalar loads).
__global__ void prep_weights(const void* __restrict__ w0,
                             const void* __restrict__ b0,
                             const void* __restrict__ wm,
                             const void* __restrict__ bm,
                             const void* __restrict__ wl,
                             const void* __restrict__ bl,
                             const void* __restrict__ wp,
                             const void* __restrict__ bp,
                             float* __restrict__ ws) {
  const bool f32 = sniff_is_f32((const unsigned short*)w0);
  int e = blockIdx.x * blockDim.x + threadIdx.x;
  if (e < 1800) {                       // w0 [25o][8c][3][3] -> [t][o][c]
    int t = e / 200, r = e % 200, o = r >> 3, c = r & 7;
    ws[OFF_W0 + e] = ldw(w0, (o * 8 + c) * 9 + t, f32);
  } else if (e < 1825) {
    ws[e] = ldw(b0, e - OFF_B0, f32);
  } else if (e < 35575) {               // wmid [l][o][c][3][3] -> [l][t][o][c]
    int q = e - OFF_WM;
    int l = q / 5625, r = q % 5625, t = r / 625, r2 = r % 625;
    int o = r2 / 25, c = r2 % 25;
    ws[e] = ldw(wm, ((l * 25 + o) * 25 + c) * 9 + t, f32);
  } else if (e < 35725) {
    ws[e] = ldw(bm, e - OFF_BM, f32);
  } else if (e < 37075) {               // wlast [6o][25c][3][3] -> [t][o][c]
    int q = e - OFF_WL;
    int t = q / 150, r = q % 150, o = r / 25, c = r % 25;
    ws[e] = ldw(wl, (o * 25 + c) * 9 + t, f32);
  } else if (e < 37081) {
    ws[e] = ldw(bl, e - OFF_BL, f32);
  } else if (e < 38431) {               // wpost: straight convert
    ws[e] = ldw(wp, e - OFF_WP, f32);
  } else if (e < WS_FLOATS) {
    ws[e] = ldw(bp, e - OFF_BP, f32);
  }
}

__global__ __launch_bounds__(NTHR) void pcnn_main(
    const void* __restrict__ inp,            // [B][8][5][5]
    const void* __restrict__ w0raw,          // for dtype sniff only
    const float* __restrict__ ws,
    void* __restrict__ out) {                // [B][3][5][5]
  __shared__ float hbuf[PPB][49][25];        // zero-padded 7x7 spatial, 25 ch
  __shared__ float inb3[PPB][3][25];         // first 3 input channels (for colors)
  __shared__ float colb[PPB][18];            // colors per patch

  const bool f32 = sniff_is_f32((const unsigned short*)w0raw);

  const int tid = threadIdx.x;
  const int pp = tid >> 5;                   // patch within block
  const int slot = tid & 31;                 // pixel slot (25 active)
  const bool active = slot < 25;
  const int s = active ? slot : 0;           // clamped: inactive lanes shadow pixel 0
  const int b = blockIdx.x * PPB + pp;
  const int py = s / 5, px = s % 5;
  const int qc = (py + 1) * 7 + (px + 1);    // padded center index

  // zero padded buffer once; borders stay zero (only interior is rewritten)
  {
    float* hf = &hbuf[0][0][0];
    for (int i = tid; i < PPB * 49 * 25; i += NTHR) hf[i] = 0.f;
  }
  __syncthreads();

  // stage input (8 ch) into padded LDS; stash first 3 ch for postconv
  if (active) {
    const size_t base = (size_t)b * 200 + slot;
    #pragma unroll
    for (int c = 0; c < 8; ++c) {
      float v = ldw(inp, base + c * 25, f32);
      hbuf[pp][qc][c] = v;
      if (c < 3) inb3[pp][c][slot] = v;
    }
  }
  __syncthreads();

  float acc[25];

  // ---- layer 0: 8 -> 25, relu ----
  #pragma unroll
  for (int o = 0; o < 25; ++o) acc[o] = ws[OFF_B0 + o];
  #pragma unroll
  for (int t = 0; t < 9; ++t) {
    const int q = (py + t / 3) * 7 + (px + t % 3);
    float hn[8];
    #pragma unroll
    for (int c = 0; c < 8; ++c) hn[c] = hbuf[pp][q][c];
    #pragma unroll
    for (int o = 0; o < 25; ++o) {
      const float* w = ws + OFF_W0 + (t * 25 + o) * 8;
      #pragma unroll
      for (int c = 0; c < 8; ++c) acc[o] = fmaf(w[c], hn[c], acc[o]);
    }
  }
  __syncthreads();
  if (active) {
    #pragma unroll
    for (int o = 0; o < 25; ++o) hbuf[pp][qc][o] = fmaxf(acc[o], 0.f);
  }
  __syncthreads();

  // ---- mid layers: 25 -> 25, relu, x6 ----
  for (int l = 0; l < 6; ++l) {
    const float* W = ws + OFF_WM + l * 5625;
    #pragma unroll
    for (int o = 0; o < 25; ++o) acc[o] = ws[OFF_BM + l * 25 + o];
    #pragma unroll
    for (int t = 0; t < 9; ++t) {
      const int q = (py + t / 3) * 7 + (px + t % 3);
      float hn[25];
      #pragma unroll
      for (int c = 0; c < 25; ++c) hn[c] = hbuf[pp][q][c];
      #pragma unroll
      for (int o = 0; o < 25; ++o) {
        const float* w = W + (t * 25 + o) * 25;
        #pragma unroll
        for (int c = 0; c < 25; ++c) acc[o] = fmaf(w[c], hn[c], acc[o]);
      }
    }
    __syncthreads();
    if (active) {
      #pragma unroll
      for (int o = 0; o < 25; ++o) hbuf[pp][qc][o] = fmaxf(acc[o], 0.f);
    }
    __syncthreads();
  }

  // ---- last layer: 25 -> 6, no relu ----
  float h6[6];
  #pragma unroll
  for (int o = 0; o < 6; ++o) h6[o] = ws[OFF_BL + o];
  #pragma unroll
  for (int t = 0; t < 9; ++t) {
    const int q = (py + t / 3) * 7 + (px + t % 3);
    float hn[25];
    #pragma unroll
    for (int c = 0; c < 25; ++c) hn[c] = hbuf[pp][q][c];
    #pragma unroll
    for (int o = 0; o < 6; ++o) {
      const float* w = ws + OFF_WL + (t * 6 + o) * 25;
      #pragma unroll
      for (int c = 0; c < 25; ++c) h6[o] = fmaf(w[c], hn[c], h6[o]);
    }
  }

  // ---- softmax over the 6 weight channels (per thread = per pixel) ----
  float m = h6[0];
  #pragma unroll
  for (int o = 1; o < 6; ++o) m = fmaxf(m, h6[o]);
  float ex[6]; float ssum = 0.f;
  #pragma unroll
  for (int o = 0; o < 6; ++o) { ex[o] = __expf(h6[o] - m); ssum += ex[o]; }
  const float inv = 1.f / ssum;

  // ---- colors: 5x5 VALID conv on first 3 input channels -> [3][6] ----
  if (slot < 18) {
    float a = ws[OFF_BP + slot];
    #pragma unroll
    for (int ic = 0; ic < 3; ++ic) {
      #pragma unroll
      for (int pix = 0; pix < 25; ++pix)
        a = fmaf(ws[OFF_WP + (slot * 3 + ic) * 25 + pix], inb3[pp][ic][pix], a);
    }
    colb[pp][slot] = a;
  }
  __syncthreads();

  // ---- filtered[b,c,y,x] = sum_w colors[b,c,w] * softmax_w ----
  if (active) {
    const size_t ob = (size_t)b * 75;
    #pragma unroll
    for (int c = 0; c < 3; ++c) {
      float v = 0.f;
      #pragma unroll
      for (int w = 0; w < 6; ++w) v = fmaf(colb[pp][c * 6 + w], ex[w], v);
      const float r = v * inv;
      if (f32) ((float*)out)[ob + c * 25 + slot] = r;
      else     ((unsigned short*)out)[ob + c * 25 + slot] = f2b(r);
    }
  }
}

extern "C" void kernel_launch(void* const* d_in, const int* in_sizes, int n_in,
                              void* d_out, int out_size, void* d_ws, size_t ws_size,
                              hipStream_t stream) {
  float* ws = (float*)d_ws;
  const int B = in_sizes[0] / 200;  // 32768

  prep_weights<<<(WS_FLOATS + 255) / 256, 256, 0, stream>>>(
      d_in[1], d_in[2], d_in[3], d_in[4], d_in[5], d_in[6], d_in[7], d_in[8], ws);
  pcnn_main<<<B / PPB, NTHR, 0, stream>>>(d_in[0], d_in[1], ws, d_out);
}

// Round 3
// 294.169 us; speedup vs baseline: 15.7152x; 15.7152x over previous
//
#include <hip/hip_runtime.h>
#include <stdint.h>

// ---------------------------------------------------------------------------
// pcnn via MFMA: each conv layer as per-output-pixel GEMM
//   out[o, b] += sum_t W_t[25x25] @ H[c, nb(p,t), b]
// mfma_f32_16x16x32_bf16: N=16 patches/block, K=32 (25ch zero-padded),
// M = 2 tiles of 16 (25 out ch). LDS: H[pix][b16][ch32] bf16, double-buffered.
// B-fragment = 1 ds_read_b128 per (p,t), shared by both M-tiles (2 MFMAs).
// Weights pre-packed by prep kernel into fragment-friendly layout in d_ws.
// ---------------------------------------------------------------------------

typedef short bf16x8 __attribute__((ext_vector_type(8)));
typedef float f32x4  __attribute__((ext_vector_type(4)));

// d_ws layout:
//  bf16 section (u16 elems):
//    WALL [7][9][32o][32c]  @ elem 0      (64512)  layer0 + 6 mid, zero-padded
//    WL   [9][16o][32c]     @ elem 64512  (4608)   last layer (6 out ch used)
//  f32 section @ byte 138240 (f32 elems):
//    BALL [7][32]  @ 0      (224)
//    BL   [32]     @ 224    (32)
//    WPOST[18][3][25] @ 256 (1350)
//    BPOST[18]     @ 1606   (18)
#define WSB_WL    64512
#define WSB_U16   69120
#define WSF_BYTE  138240
#define WSF_BALL  0
#define WSF_BL    224
#define WSF_WPOST 256
#define WSF_BPOST 1606
#define WSF_N     1624

// LDS layout (bytes)
#define LDS_HA   0       // bf16 H buf A: [25pix][16b][32ch] = 25600 B
#define LDS_HB   25600   // bf16 H buf B
#define LDS_IN3  51200   // f32 [16b][3c][25pix] = 4800 B
#define LDS_COL  56000   // f32 [16b][18oc] = 1152 B
#define LDS_TOT  57152
// overlays on dead HA after last mid layer:
#define LDS_LOG  0       // f32 [25p][16b][8pad] = 12800 B
#define LDS_SM   12800   // f32 [25p][16b][6]    = 9600 B

__device__ __forceinline__ float b2f(unsigned short u) {
  union { unsigned int u; float f; } v; v.u = ((unsigned int)u) << 16; return v.f;
}
__device__ __forceinline__ unsigned short f2b(float f) {
  union { float f; unsigned int u; } v; v.f = f;
  unsigned int r = v.u + 0x7fffu + ((v.u >> 16) & 1u);  // RNE
  return (unsigned short)(r >> 16);
}
// dtype sniff: f32 data read as u16 shows huge bf16-exponent fields
__device__ __forceinline__ bool sniff_is_f32(const void* w0raw) {
  const unsigned short* q = (const unsigned short*)w0raw;
  int hits = 0;
  #pragma unroll
  for (int i = 0; i < 64; ++i) {
    unsigned int e = (q[i] >> 7) & 0xFFu;
    if (e >= 130u) ++hits;
  }
  return hits > 0;
}
__device__ __forceinline__ float ldw(const void* p, long idx, bool f32) {
  return f32 ? ((const float*)p)[idx] : b2f(((const unsigned short*)p)[idx]);
}

// ---------------- weight pre-pack -----------------------------------------
__global__ void prep_weights(const void* __restrict__ w0,
                             const void* __restrict__ b0,
                             const void* __restrict__ wm,
                             const void* __restrict__ bm,
                             const void* __restrict__ wl,
                             const void* __restrict__ bl,
                             const void* __restrict__ wp,
                             const void* __restrict__ bp,
                             unsigned short* __restrict__ wsb,
                             float* __restrict__ wsf) {
  const bool f32 = sniff_is_f32(w0);
  int e = blockIdx.x * blockDim.x + threadIdx.x;
  if (e < WSB_WL) {                       // WALL[l][t][o][c]
    int l = e / 9216, r = e % 9216, t = r / 1024, r2 = r % 1024;
    int o = r2 / 32, c = r2 % 32;
    float v = 0.f;
    if (l == 0) { if (o < 25 && c < 8)  v = ldw(w0, (o * 8 + c) * 9 + t, f32); }
    else        { if (o < 25 && c < 25) v = ldw(wm, (((l - 1) * 25 + o) * 25 + c) * 9 + t, f32); }
    wsb[e] = f2b(v);
  } else if (e < WSB_U16) {               // WL[t][o][c]
    int q = e - WSB_WL;
    int t = q / 512, r = q % 512, o = r / 32, c = r % 32;
    float v = 0.f;
    if (o < 6 && c < 25) v = ldw(wl, (o * 25 + c) * 9 + t, f32);
    wsb[e] = f2b(v);
  } else {
    int q = e - WSB_U16;
    if (q < 224) {                        // BALL[l][32]
      int l = q / 32, o = q % 32;
      float v = 0.f;
      if (o < 25) v = (l == 0) ? ldw(b0, o, f32) : ldw(bm, (l - 1) * 25 + o, f32);
      wsf[WSF_BALL + q] = v;
    } else if (q < 256) {                 // BL[32]
      int o = q - 224;
      wsf[WSF_BL + o] = (o < 6) ? ldw(bl, o, f32) : 0.f;
    } else if (q < 256 + 1350) {
      wsf[WSF_WPOST + (q - 256)] = ldw(wp, q - 256, f32);
    } else if (q < 256 + 1350 + 18) {
      wsf[WSF_BPOST + (q - 1606)] = ldw(bp, q - 1606, f32);
    }
  }
}

// ---------------- main kernel ----------------------------------------------
__global__ __launch_bounds__(256) void pcnn_mfma(
    const void* __restrict__ inp,
    const void* __restrict__ w0raw,
    const unsigned short* __restrict__ wsb,
    const float* __restrict__ wsf,
    void* __restrict__ out) {
  __shared__ __align__(16) unsigned char lds[LDS_TOT];
  const bool f32m = sniff_is_f32(w0raw);
  const int tid  = threadIdx.x;
  const int lane = tid & 63;
  const int wv   = tid >> 6;             // wave 0..3: pixel range
  const int col  = lane & 15;            // MFMA n (patch) / m (out ch)
  const int quad = lane >> 4;            // MFMA k-block / row-block
  const int g    = blockIdx.x;           // group of 16 patches

  // zero both H buffers (incl. ch 25..31 zero-pad, relied on by K=32 MFMA)
  for (int i = tid; i < 51200 / 4; i += 256) ((unsigned int*)lds)[i] = 0u;
  __syncthreads();

  // stage input: [b][8c][25pix] -> HA[pix][b][c], first 3 ch also to IN3 (f32)
  for (int e = tid; e < 3200; e += 256) {
    int b = e / 200, r = e % 200, c = r / 25, pix = r % 25;
    float v = ldw(inp, (long)g * 3200 + e, f32m);
    ((unsigned short*)(lds + LDS_HA))[(pix * 16 + b) * 32 + c] = f2b(v);
    if (c < 3) ((float*)(lds + LDS_IN3))[(b * 3 + c) * 25 + pix] = v;
  }
  __syncthreads();

  const int p0 = wv * 6, p1 = (wv == 3) ? 25 : p0 + 6;
  const int laneoff = col * 64 + quad * 16;  // byte offset inside one pixel slab

  // ---- 7 relu conv layers (layer0 8->25 zero-padded to same shape) ----
  for (int l = 0; l < 7; ++l) {
    const unsigned short* WA = wsb + l * 9216;
    bf16x8 af0[9], af1[9];
    #pragma unroll
    for (int t = 0; t < 9; ++t) {
      af0[t] = *(const bf16x8*)(WA + (t * 32 + col) * 32 + quad * 8);
      af1[t] = *(const bf16x8*)(WA + (t * 32 + 16 + col) * 32 + quad * 8);
    }
    const f32x4 bias0 = *(const f32x4*)(wsf + WSF_BALL + l * 32 + quad * 4);
    const f32x4 bias1 = *(const f32x4*)(wsf + WSF_BALL + l * 32 + 16 + quad * 4);
    const unsigned char* hin  = lds + ((l & 1) ? LDS_HB : LDS_HA);
    unsigned char*       hout = lds + ((l & 1) ? LDS_HA : LDS_HB);

    for (int p = p0; p < p1; ++p) {
      const int py = p / 5, px = p % 5;
      f32x4 a0 = bias0, a1 = bias1;
      const int bofs = p * 1024 + laneoff - 6144;
      #define TAPM(dy, dx) do { \
        bf16x8 bf = *(const bf16x8*)(hin + bofs + (((dy) * 5 + (dx) + 6) * 1024)); \
        a0 = __builtin_amdgcn_mfma_f32_16x16x32_bf16(af0[((dy)+1)*3+(dx)+1], bf, a0, 0, 0, 0); \
        a1 = __builtin_amdgcn_mfma_f32_16x16x32_bf16(af1[((dy)+1)*3+(dx)+1], bf, a1, 0, 0, 0); \
      } while (0)
      if (py > 0) { if (px > 0) TAPM(-1,-1); TAPM(-1,0); if (px < 4) TAPM(-1,1); }
      {            if (px > 0) TAPM( 0,-1); TAPM( 0,0); if (px < 4) TAPM( 0,1); }
      if (py < 4) { if (px > 0) TAPM( 1,-1); TAPM( 1,0); if (px < 4) TAPM( 1,1); }
      #undef TAPM

      // relu + cvt + store: rows quad*4..+3 (mtile0: ch r, mtile1: ch 16+r)
      uint2 s0;
      s0.x = (unsigned int)f2b(fmaxf(a0[0], 0.f)) | ((unsigned int)f2b(fmaxf(a0[1], 0.f)) << 16);
      s0.y = (unsigned int)f2b(fmaxf(a0[2], 0.f)) | ((unsigned int)f2b(fmaxf(a0[3], 0.f)) << 16);
      *(uint2*)(hout + p * 1024 + col * 64 + quad * 8) = s0;
      if (quad < 2) {
        uint2 s1;
        s1.x = (unsigned int)f2b(fmaxf(a1[0], 0.f)) | ((unsigned int)f2b(fmaxf(a1[1], 0.f)) << 16);
        s1.y = (unsigned int)f2b(fmaxf(a1[2], 0.f)) | ((unsigned int)f2b(fmaxf(a1[3], 0.f)) << 16);
        *(uint2*)(hout + p * 1024 + col * 64 + 32 + quad * 8) = s1;
      } else if (quad == 2) {  // ch 24 only
        *(unsigned short*)(hout + p * 1024 + col * 64 + 48) = f2b(fmaxf(a1[0], 0.f));
      }
    }
    __syncthreads();
  }

  // ---- last layer: 25 -> 6 logits (no relu), f32 into LOG overlay (dead HA)
  {
    const unsigned short* WA = wsb + WSB_WL;
    bf16x8 afl[9];
    #pragma unroll
    for (int t = 0; t < 9; ++t)
      afl[t] = *(const bf16x8*)(WA + (t * 16 + col) * 32 + quad * 8);
    const f32x4 biasl = *(const f32x4*)(wsf + WSF_BL + quad * 4);
    const unsigned char* hin = lds + LDS_HB;   // final hidden lives in B
    float* logits = (float*)(lds + LDS_LOG);

    for (int p = p0; p < p1; ++p) {
      const int py = p / 5, px = p % 5;
      f32x4 a0 = biasl;
      const int bofs = p * 1024 + laneoff - 6144;
      #define TAPL(dy, dx) do { \
        bf16x8 bf = *(const bf16x8*)(hin + bofs + (((dy) * 5 + (dx) + 6) * 1024)); \
        a0 = __builtin_amdgcn_mfma_f32_16x16x32_bf16(afl[((dy)+1)*3+(dx)+1], bf, a0, 0, 0, 0); \
      } while (0)
      if (py > 0) { if (px > 0) TAPL(-1,-1); TAPL(-1,0); if (px < 4) TAPL(-1,1); }
      {            if (px > 0) TAPL( 0,-1); TAPL( 0,0); if (px < 4) TAPL( 0,1); }
      if (py < 4) { if (px > 0) TAPL( 1,-1); TAPL( 1,0); if (px < 4) TAPL( 1,1); }
      #undef TAPL
      float* lp = logits + (p * 16 + col) * 8;
      if (quad == 0) {            // rows 0..3
        *(f32x4*)lp = a0;
      } else if (quad == 1) {     // rows 4,5
        lp[4] = a0[0]; lp[5] = a0[1];
      }
    }
  }
  __syncthreads();

  // ---- epilogue: colors (postconv) + softmax ----
  {
    const float* in3 = (const float*)(lds + LDS_IN3);
    float* colors = (float*)(lds + LDS_COL);
    const float* WP = wsf + WSF_WPOST;
    const float* BP = wsf + WSF_BPOST;
    for (int j = tid; j < 288; j += 256) {
      int b = j / 18, oc = j % 18;
      float s = BP[oc];
      #pragma unroll
      for (int ic = 0; ic < 3; ++ic) {
        #pragma unroll
        for (int pix = 0; pix < 25; ++pix)
          s = fmaf(WP[(oc * 3 + ic) * 25 + pix], in3[(b * 3 + ic) * 25 + pix], s);
      }
      colors[b * 18 + oc] = s;
    }
    const float* logits = (const float*)(lds + LDS_LOG);
    float* smb = (float*)(lds + LDS_SM);
    for (int j = tid; j < 400; j += 256) {
      const float* lp = logits + j * 8;
      float m = lp[0];
      #pragma unroll
      for (int k = 1; k < 6; ++k) m = fmaxf(m, lp[k]);
      float e[6], s = 0.f;
      #pragma unroll
      for (int k = 0; k < 6; ++k) { e[k] = __expf(lp[k] - m); s += e[k]; }
      const float inv = 1.f / s;
      #pragma unroll
      for (int k = 0; k < 6; ++k) smb[j * 6 + k] = e[k] * inv;
    }
  }
  __syncthreads();

  // ---- mix + store: out[b][c][p] = sum_w colors[b][c*6+w] * sm[p][b][w] ----
  {
    const float* colors = (const float*)(lds + LDS_COL);
    const float* smb = (const float*)(lds + LDS_SM);
    for (int e = tid; e < 1200; e += 256) {
      int b = e / 75, r = e % 75, c = r / 25, p = r % 25;
      float v = 0.f;
      #pragma unroll
      for (int w = 0; w < 6; ++w)
        v = fmaf(colors[b * 18 + c * 6 + w], smb[(p * 16 + b) * 6 + w], v);
      const long oidx = (long)g * 1200 + e;
      if (f32m) ((float*)out)[oidx] = v;
      else      ((unsigned short*)out)[oidx] = f2b(v);
    }
  }
}

extern "C" void kernel_launch(void* const* d_in, const int* in_sizes, int n_in,
                              void* d_out, int out_size, void* d_ws, size_t ws_size,
                              hipStream_t stream) {
  unsigned short* wsb = (unsigned short*)d_ws;
  float* wsf = (float*)((char*)d_ws + WSF_BYTE);
  const int B = in_sizes[0] / 200;  // 32768

  const int prep_n = WSB_U16 + WSF_N;  // 70744
  prep_weights<<<(prep_n + 255) / 256, 256, 0, stream>>>(
      d_in[1], d_in[2], d_in[3], d_in[4], d_in[5], d_in[6], d_in[7], d_in[8],
      wsb, wsf);
  pcnn_mfma<<<B / 16, 256, 0, stream>>>(d_in[0], d_in[1], wsb, wsf, d_out);
}